// Round 16
// baseline (45.470 us; speedup 1.0000x reference)
//
#include <hip/hip_runtime.h>

typedef float f32x4 __attribute__((ext_vector_type(4)));

#define D_IN 1024

// tanh(x) = 1 - 2/(exp(2x)+1): v_exp + v_rcp, robust for all x
__device__ __forceinline__ float fast_tanh(float x) {
  float e = __expf(2.0f * x);
  return 1.0f - 2.0f * __builtin_amdgcn_rcpf(e + 1.0f);
}

// ---------------------------------------------------------------------------
// k1 v2: dots[r][j] = x[r] . W1[j], j=0..3.
// 4 rows/wave, 16 lanes/row (p = lane&15 owns floats [i*64 + p*4, +4)).
// Grid = B/16 = 2048 blocks -> 8 waves/SIMD (streaming occupancy).
// Per-instruction: 256B contiguous per row-group; W1 LDS reads broadcast
// across row-groups, 2-way bank aliasing only (free). 4-level shfl reduce.
// ---------------------------------------------------------------------------
__global__ __launch_bounds__(256) void dots_kernel(
    const float* __restrict__ x, const float* __restrict__ W1,
    float* __restrict__ dots, int B) {
  __shared__ f32x4 W1L[1024];  // W1L[j*256 + i*16 + p] = W1[j][ (i*16+p)*4 ..+4 ]

  const int tid = threadIdx.x;
  {
    const f32x4* wp = reinterpret_cast<const f32x4*>(W1);
#pragma unroll
    for (int k = 0; k < 4; ++k) W1L[k * 256 + tid] = wp[k * 256 + tid];
  }
  __syncthreads();

  const int lane = tid & 63;
  const int p = lane & 15;
  const int wave = blockIdx.x * 4 + (tid >> 6);
  const int row = wave * 4 + (lane >> 4);
  if (row >= B) return;

  const f32x4* xr = reinterpret_cast<const f32x4*>(x + (size_t)row * D_IN);
  float acc[4] = {0.f, 0.f, 0.f, 0.f};

#pragma unroll
  for (int i = 0; i < 16; ++i) {
    f32x4 xk = __builtin_nontemporal_load(xr + i * 16 + p);
#pragma unroll
    for (int j = 0; j < 4; ++j) {
      f32x4 w = W1L[j * 256 + i * 16 + p];
      acc[j] = fmaf(xk.x, w.x, acc[j]);
      acc[j] = fmaf(xk.y, w.y, acc[j]);
      acc[j] = fmaf(xk.z, w.z, acc[j]);
      acc[j] = fmaf(xk.w, w.w, acc[j]);
    }
  }

  // reduce each dot over the 16 lanes of this row (4 butterfly levels)
#pragma unroll
  for (int j = 0; j < 4; ++j) {
    acc[j] += __shfl_xor(acc[j], 1);
    acc[j] += __shfl_xor(acc[j], 2);
    acc[j] += __shfl_xor(acc[j], 4);
    acc[j] += __shfl_xor(acc[j], 8);
  }
  if (p < 4) {
    float outv = (p == 0) ? acc[0] : (p == 1) ? acc[1] : (p == 2) ? acc[2] : acc[3];
    dots[(size_t)row * 4 + p] = outv;  // 16B per row, coalesced within group
  }
}

// ---------------------------------------------------------------------------
// k2: tail (unchanged from round 15, validated). Per row: uniform 16B load of
// dots[r] -> tanh/sincos -> rank-1 product state -> qf_i = s^T M_i s -> mu/lv.
// ---------------------------------------------------------------------------
__global__ __launch_bounds__(256) void tail_kernel(
    const float* __restrict__ dots, const float* __restrict__ b1,
    const float* __restrict__ theta,
    const float* __restrict__ Wmu, const float* __restrict__ bmu,
    const float* __restrict__ Wlv, const float* __restrict__ blv,
    float* __restrict__ out, int B) {
  __shared__ float Vre[16][17];
  __shared__ float Vim[16][17];
  __shared__ float Mlds[4][16][16];

  const int tid = threadIdx.x;

  // ---- prologue: evolve V on threads 0..15 ----
  if (tid < 16) {
    float re[16], im[16];
#pragma unroll
    for (int z = 0; z < 16; ++z) { re[z] = 0.f; im[z] = 0.f; }
    re[tid] = 1.f;
    for (int layer = 0; layer < 2; ++layer) {
#pragma unroll
      for (int q = 0; q < 4; ++q) {
        float th = theta[layer * 4 + q];
        float s, c;
        __sincosf(0.5f * th, &s, &c);
        // Rx
#pragma unroll
        for (int z = 0; z < 16; ++z) {
          if (!((z >> q) & 1)) {
            int z1 = z | (1 << q);
            float ar = re[z], ai = im[z], br = re[z1], bi = im[z1];
            re[z]  = c * ar + s * bi;  im[z]  = c * ai - s * br;
            re[z1] = c * br + s * ai;  im[z1] = c * bi - s * ar;
          }
        }
        // Ry
#pragma unroll
        for (int z = 0; z < 16; ++z) {
          if (!((z >> q) & 1)) {
            int z1 = z | (1 << q);
            float ar = re[z], ai = im[z], br = re[z1], bi = im[z1];
            re[z]  = c * ar - s * br;  im[z]  = c * ai - s * bi;
            re[z1] = s * ar + c * br;  im[z1] = s * ai + c * bi;
          }
        }
        // Rz
#pragma unroll
        for (int z = 0; z < 16; ++z) {
          if (!((z >> q) & 1)) {
            int z1 = z | (1 << q);
            float ar = re[z], ai = im[z], br = re[z1], bi = im[z1];
            re[z]  = c * ar + s * ai;  im[z]  = c * ai - s * ar;
            re[z1] = c * br - s * bi;  im[z1] = c * bi + s * br;
          }
        }
      }
      // CNOT ring (0,1)(1,2)(2,3)(3,0)
      const int cqs[4] = {0, 1, 2, 3};
      const int tqs[4] = {1, 2, 3, 0};
#pragma unroll
      for (int gIdx = 0; gIdx < 4; ++gIdx) {
#pragma unroll
        for (int z = 0; z < 16; ++z) {
          if (((z >> cqs[gIdx]) & 1) && !((z >> tqs[gIdx]) & 1)) {
            int z1 = z | (1 << tqs[gIdx]);
            float tr = re[z], ti = im[z];
            re[z] = re[z1];  im[z] = im[z1];
            re[z1] = tr;     im[z1] = ti;
          }
        }
      }
    }
#pragma unroll
    for (int z = 0; z < 16; ++z) { Vre[z][tid] = re[z]; Vim[z][tid] = im[z]; }
  }
  __syncthreads();

  // ---- prologue: M formation ----
  {
    const int i = tid >> 6, a = (tid >> 2) & 15, b0 = (tid & 3) * 4;
    float ra[16], ia[16];
#pragma unroll
    for (int z = 0; z < 16; ++z) { ra[z] = Vre[z][a]; ia[z] = Vim[z][a]; }
#pragma unroll
    for (int k = 0; k < 4; ++k) {
      const int b = b0 + k;
      float acc = 0.f;
#pragma unroll
      for (int z = 0; z < 16; ++z) {
        float sg = ((z >> (3 - i)) & 1) ? -1.f : 1.f;
        acc += sg * (ra[z] * Vre[z][b] + ia[z] * Vim[z][b]);
      }
      Mlds[i][a][b] = acc;
    }
  }
  __syncthreads();

  // ---- main-loop invariants ----
  const int lane = tid & 63;
  const int wave = blockIdx.x * 4 + (tid >> 6);
  const int nwaves = gridDim.x * 4;
  const int g = lane >> 4;
  const int mz = lane & 15;

  float Mr[16];
#pragma unroll
  for (int k = 0; k < 16; ++k) Mr[k] = Mlds[g][mz][k];

  float b1r[4];
#pragma unroll
  for (int j = 0; j < 4; ++j) b1r[j] = b1[j];

  float wmuP[4], wlvP[4];
#pragma unroll
  for (int k = 0; k < 4; ++k) {
    wmuP[k] = Wmu[lane * 4 + (g ^ k)];
    wlvP[k] = Wlv[lane * 4 + (g ^ k)];
  }
  const float bmur = bmu[lane], blvr = blv[lane];
  const size_t lv_base = (size_t)B * 64;

  for (int r = wave; r < B; r += nwaves) {
    const float4 dv = *reinterpret_cast<const float4*>(dots + (size_t)r * 4);

    // ---- angles -> half-angle (cos, sin) ----
    float cq[4], sq[4];
    __sincosf(0.5f * fast_tanh(dv.x + b1r[0]), &sq[0], &cq[0]);
    __sincosf(0.5f * fast_tanh(dv.y + b1r[1]), &sq[1], &cq[1]);
    __sincosf(0.5f * fast_tanh(dv.z + b1r[2]), &sq[2], &cq[2]);
    __sincosf(0.5f * fast_tanh(dv.w + b1r[3]), &sq[3], &cq[3]);

    // rank-1 factors of the product state: sv[z] = A[z&3] * Bf[z>>2]
    const float A0 = cq[0] * cq[1], A1 = sq[0] * cq[1];
    const float A2 = cq[0] * sq[1], A3 = sq[0] * sq[1];
    const float B0 = cq[2] * cq[3], B1 = sq[2] * cq[3];
    const float B2 = cq[2] * sq[3], B3 = sq[2] * sq[3];

    // tdot = M_g[mz][:] . sv
    float t0 = fmaf(Mr[3], A3, fmaf(Mr[2], A2, fmaf(Mr[1], A1, Mr[0] * A0)));
    float t1 = fmaf(Mr[7], A3, fmaf(Mr[6], A2, fmaf(Mr[5], A1, Mr[4] * A0)));
    float t2 = fmaf(Mr[11], A3, fmaf(Mr[10], A2, fmaf(Mr[9], A1, Mr[8] * A0)));
    float t3 = fmaf(Mr[15], A3, fmaf(Mr[14], A2, fmaf(Mr[13], A1, Mr[12] * A0)));
    float tdot = fmaf(t3, B3, fmaf(t2, B2, fmaf(t1, B1, t0 * B0)));

    // sv[mz] via per-bit selects
    float svm = ((mz & 1) ? sq[0] : cq[0]);
    svm *= ((mz & 2) ? sq[1] : cq[1]);
    svm *= ((mz & 4) ? sq[2] : cq[2]);
    svm *= ((mz & 8) ? sq[3] : cq[3]);

    float pacc = tdot * svm;
#pragma unroll
    for (int off = 8; off; off >>= 1) pacc += __shfl_xor(pacc, off);
    // pacc = qf_g; exchange across 16-lane groups
    float v1 = __shfl_xor(pacc, 16);  // qf_{g^1}
    float v2 = __shfl_xor(pacc, 32);  // qf_{g^2}
    float v3 = __shfl_xor(v1, 32);    // qf_{g^3}

    float mu = fmaf(v3, wmuP[3], fmaf(v2, wmuP[2], fmaf(v1, wmuP[1], fmaf(pacc, wmuP[0], bmur))));
    float lv = fmaf(v3, wlvP[3], fmaf(v2, wlvP[2], fmaf(v1, wlvP[1], fmaf(pacc, wlvP[0], blvr))));
    __builtin_nontemporal_store(mu, out + (size_t)r * 64 + lane);
    __builtin_nontemporal_store(lv, out + lv_base + (size_t)r * 64 + lane);
  }
}

extern "C" void kernel_launch(void* const* d_in, const int* in_sizes, int n_in,
                              void* d_out, int out_size, void* d_ws, size_t ws_size,
                              hipStream_t stream) {
  const float* x   = (const float*)d_in[0];
  const float* W1  = (const float*)d_in[1];
  const float* b1  = (const float*)d_in[2];
  const float* qp  = (const float*)d_in[3];
  const float* Wmu = (const float*)d_in[4];
  const float* bmu = (const float*)d_in[5];
  const float* Wlv = (const float*)d_in[6];
  const float* blv = (const float*)d_in[7];
  float* out = (float*)d_out;
  float* dots = (float*)d_ws;  // B*4 floats = 512 KB scratch

  const int B = out_size / 128;  // out = mu(B,64) ++ logvar(B,64)

  // k1: 4 rows/wave, 4 waves/block -> 16 rows/block; B/16 = 2048 blocks
  int blocks1 = (B + 15) / 16;
  dots_kernel<<<blocks1, 256, 0, stream>>>(x, W1, dots, B);

  // k2: 4 waves/block, grid-stride rows
  int blocks2 = (B + 31) / 32;
  if (blocks2 > 1024) blocks2 = 1024;
  tail_kernel<<<blocks2, 256, 0, stream>>>(dots, b1, qp, Wmu, bmu, Wlv, blv,
                                           out, B);
}

// Round 17
// 43.311 us; speedup vs baseline: 1.0498x; 1.0498x over previous
//
#include <hip/hip_runtime.h>

typedef float f32x4 __attribute__((ext_vector_type(4)));

#define D_IN 1024

// tanh(x) = 1 - 2/(exp(2x)+1): v_exp + v_rcp, robust for all x
__device__ __forceinline__ float fast_tanh(float x) {
  float e = __expf(2.0f * x);
  return 1.0f - 2.0f * __builtin_amdgcn_rcpf(e + 1.0f);
}

// ---------------------------------------------------------------------------
// k1 v3: dots[r][j] = x[r] . W1[j]. Round-6's VALIDATED dot phase verbatim:
// row-per-wave, plain (cacheable) loads of 4x 1KB contiguous per row,
// W1 from LDS, register prefetch pipeline, fused butterfly (no redistribute:
// lanes 0/16/32/48 hold dot_{0,2,1,3} after the reduce and store directly).
// Grid 2048 blocks x 4 waves = 8 waves/SIMD; 4 rows/wave grid-stride.
// ---------------------------------------------------------------------------
__global__ __launch_bounds__(256) void dots_kernel(
    const float* __restrict__ x, const float* __restrict__ W1,
    float* __restrict__ dots, int B) {
  __shared__ f32x4 W1L[1024];  // [j*256 + k*64 + lane]

  const int tid = threadIdx.x;
  {
    const f32x4* wp = reinterpret_cast<const f32x4*>(W1);
#pragma unroll
    for (int k = 0; k < 4; ++k) W1L[k * 256 + tid] = wp[k * 256 + tid];
  }
  __syncthreads();

  const int lane = tid & 63;
  const int wave = blockIdx.x * 4 + (tid >> 6);
  const int nwaves = gridDim.x * 4;
  const bool bit4 = (lane & 16) != 0;
  const bool bit5 = (lane & 32) != 0;
  const int f = 2 * (int)bit4 + (int)bit5;  // which dot this lane-group reduces

  int r = wave;
  if (r >= B) return;

  f32x4 xv[4];
  {
    const f32x4* xp = reinterpret_cast<const f32x4*>(x + (size_t)r * D_IN);
#pragma unroll
    for (int k = 0; k < 4; ++k) xv[k] = xp[k * 64 + lane];
  }

  while (true) {
    // ---- dot partials: W1 frags from LDS, x from regs (last use of xv) ----
    float acc[4] = {0.f, 0.f, 0.f, 0.f};
#pragma unroll
    for (int k = 0; k < 4; ++k) {
      f32x4 xk = xv[k];
#pragma unroll
      for (int j = 0; j < 4; ++j) {
        f32x4 w = W1L[j * 256 + k * 64 + lane];
        acc[j] = fmaf(xk.x, w.x, acc[j]);
        acc[j] = fmaf(xk.y, w.y, acc[j]);
        acc[j] = fmaf(xk.z, w.z, acc[j]);
        acc[j] = fmaf(xk.w, w.w, acc[j]);
      }
    }

    // ---- prefetch next row into the same regs ----
    const int rn = r + nwaves;
    if (rn < B) {
      const f32x4* xp = reinterpret_cast<const f32x4*>(x + (size_t)rn * D_IN);
#pragma unroll
      for (int k = 0; k < 4; ++k) xv[k] = xp[k * 64 + lane];
    }

    // ---- fused butterfly: 7 shfls reduce all 4 dots (validated round-6) ----
    float u = bit5 ? acc[1] : acc[0];
    u += __shfl_xor(bit5 ? acc[0] : acc[1], 32);
    float v = bit5 ? acc[3] : acc[2];
    v += __shfl_xor(bit5 ? acc[2] : acc[3], 32);
    float w = bit4 ? v : u;
    w += __shfl_xor(bit4 ? u : v, 16);
#pragma unroll
    for (int off = 8; off; off >>= 1) w += __shfl_xor(w, off);

    // lane group leader stores dot_f; lanes 0,16,32,48 -> f = 0,2,1,3
    if ((lane & 15) == 0) dots[(size_t)r * 4 + f] = w;

    if (rn >= B) break;
    r = rn;
  }
}

// ---------------------------------------------------------------------------
// k2: tail (unchanged, validated). Per row: uniform 16B load of dots[r] ->
// tanh/sincos -> rank-1 product state -> qf_i = s^T M_i s -> mu/logvar.
// ---------------------------------------------------------------------------
__global__ __launch_bounds__(256) void tail_kernel(
    const float* __restrict__ dots, const float* __restrict__ b1,
    const float* __restrict__ theta,
    const float* __restrict__ Wmu, const float* __restrict__ bmu,
    const float* __restrict__ Wlv, const float* __restrict__ blv,
    float* __restrict__ out, int B) {
  __shared__ float Vre[16][17];
  __shared__ float Vim[16][17];
  __shared__ float Mlds[4][16][16];

  const int tid = threadIdx.x;

  // ---- prologue: evolve V on threads 0..15 ----
  if (tid < 16) {
    float re[16], im[16];
#pragma unroll
    for (int z = 0; z < 16; ++z) { re[z] = 0.f; im[z] = 0.f; }
    re[tid] = 1.f;
    for (int layer = 0; layer < 2; ++layer) {
#pragma unroll
      for (int q = 0; q < 4; ++q) {
        float th = theta[layer * 4 + q];
        float s, c;
        __sincosf(0.5f * th, &s, &c);
        // Rx
#pragma unroll
        for (int z = 0; z < 16; ++z) {
          if (!((z >> q) & 1)) {
            int z1 = z | (1 << q);
            float ar = re[z], ai = im[z], br = re[z1], bi = im[z1];
            re[z]  = c * ar + s * bi;  im[z]  = c * ai - s * br;
            re[z1] = c * br + s * ai;  im[z1] = c * bi - s * ar;
          }
        }
        // Ry
#pragma unroll
        for (int z = 0; z < 16; ++z) {
          if (!((z >> q) & 1)) {
            int z1 = z | (1 << q);
            float ar = re[z], ai = im[z], br = re[z1], bi = im[z1];
            re[z]  = c * ar - s * br;  im[z]  = c * ai - s * bi;
            re[z1] = s * ar + c * br;  im[z1] = s * ai + c * bi;
          }
        }
        // Rz
#pragma unroll
        for (int z = 0; z < 16; ++z) {
          if (!((z >> q) & 1)) {
            int z1 = z | (1 << q);
            float ar = re[z], ai = im[z], br = re[z1], bi = im[z1];
            re[z]  = c * ar + s * ai;  im[z]  = c * ai - s * ar;
            re[z1] = c * br - s * bi;  im[z1] = c * bi + s * br;
          }
        }
      }
      // CNOT ring (0,1)(1,2)(2,3)(3,0)
      const int cqs[4] = {0, 1, 2, 3};
      const int tqs[4] = {1, 2, 3, 0};
#pragma unroll
      for (int gIdx = 0; gIdx < 4; ++gIdx) {
#pragma unroll
        for (int z = 0; z < 16; ++z) {
          if (((z >> cqs[gIdx]) & 1) && !((z >> tqs[gIdx]) & 1)) {
            int z1 = z | (1 << tqs[gIdx]);
            float tr = re[z], ti = im[z];
            re[z] = re[z1];  im[z] = im[z1];
            re[z1] = tr;     im[z1] = ti;
          }
        }
      }
    }
#pragma unroll
    for (int z = 0; z < 16; ++z) { Vre[z][tid] = re[z]; Vim[z][tid] = im[z]; }
  }
  __syncthreads();

  // ---- prologue: M formation ----
  {
    const int i = tid >> 6, a = (tid >> 2) & 15, b0 = (tid & 3) * 4;
    float ra[16], ia[16];
#pragma unroll
    for (int z = 0; z < 16; ++z) { ra[z] = Vre[z][a]; ia[z] = Vim[z][a]; }
#pragma unroll
    for (int k = 0; k < 4; ++k) {
      const int b = b0 + k;
      float acc = 0.f;
#pragma unroll
      for (int z = 0; z < 16; ++z) {
        float sg = ((z >> (3 - i)) & 1) ? -1.f : 1.f;
        acc += sg * (ra[z] * Vre[z][b] + ia[z] * Vim[z][b]);
      }
      Mlds[i][a][b] = acc;
    }
  }
  __syncthreads();

  // ---- main-loop invariants ----
  const int lane = tid & 63;
  const int wave = blockIdx.x * 4 + (tid >> 6);
  const int nwaves = gridDim.x * 4;
  const int g = lane >> 4;
  const int mz = lane & 15;

  float Mr[16];
#pragma unroll
  for (int k = 0; k < 16; ++k) Mr[k] = Mlds[g][mz][k];

  float b1r[4];
#pragma unroll
  for (int j = 0; j < 4; ++j) b1r[j] = b1[j];

  float wmuP[4], wlvP[4];
#pragma unroll
  for (int k = 0; k < 4; ++k) {
    wmuP[k] = Wmu[lane * 4 + (g ^ k)];
    wlvP[k] = Wlv[lane * 4 + (g ^ k)];
  }
  const float bmur = bmu[lane], blvr = blv[lane];
  const size_t lv_base = (size_t)B * 64;

  for (int r = wave; r < B; r += nwaves) {
    const float4 dv = *reinterpret_cast<const float4*>(dots + (size_t)r * 4);

    // ---- angles -> half-angle (cos, sin) ----
    float cq[4], sq[4];
    __sincosf(0.5f * fast_tanh(dv.x + b1r[0]), &sq[0], &cq[0]);
    __sincosf(0.5f * fast_tanh(dv.y + b1r[1]), &sq[1], &cq[1]);
    __sincosf(0.5f * fast_tanh(dv.z + b1r[2]), &sq[2], &cq[2]);
    __sincosf(0.5f * fast_tanh(dv.w + b1r[3]), &sq[3], &cq[3]);

    // rank-1 factors of the product state: sv[z] = A[z&3] * Bf[z>>2]
    const float A0 = cq[0] * cq[1], A1 = sq[0] * cq[1];
    const float A2 = cq[0] * sq[1], A3 = sq[0] * sq[1];
    const float B0 = cq[2] * cq[3], B1 = sq[2] * cq[3];
    const float B2 = cq[2] * sq[3], B3 = sq[2] * sq[3];

    // tdot = M_g[mz][:] . sv
    float t0 = fmaf(Mr[3], A3, fmaf(Mr[2], A2, fmaf(Mr[1], A1, Mr[0] * A0)));
    float t1 = fmaf(Mr[7], A3, fmaf(Mr[6], A2, fmaf(Mr[5], A1, Mr[4] * A0)));
    float t2 = fmaf(Mr[11], A3, fmaf(Mr[10], A2, fmaf(Mr[9], A1, Mr[8] * A0)));
    float t3 = fmaf(Mr[15], A3, fmaf(Mr[14], A2, fmaf(Mr[13], A1, Mr[12] * A0)));
    float tdot = fmaf(t3, B3, fmaf(t2, B2, fmaf(t1, B1, t0 * B0)));

    // sv[mz] via per-bit selects
    float svm = ((mz & 1) ? sq[0] : cq[0]);
    svm *= ((mz & 2) ? sq[1] : cq[1]);
    svm *= ((mz & 4) ? sq[2] : cq[2]);
    svm *= ((mz & 8) ? sq[3] : cq[3]);

    float pacc = tdot * svm;
#pragma unroll
    for (int off = 8; off; off >>= 1) pacc += __shfl_xor(pacc, off);
    // pacc = qf_g; exchange across 16-lane groups
    float v1 = __shfl_xor(pacc, 16);  // qf_{g^1}
    float v2 = __shfl_xor(pacc, 32);  // qf_{g^2}
    float v3 = __shfl_xor(v1, 32);    // qf_{g^3}

    float mu = fmaf(v3, wmuP[3], fmaf(v2, wmuP[2], fmaf(v1, wmuP[1], fmaf(pacc, wmuP[0], bmur))));
    float lv = fmaf(v3, wlvP[3], fmaf(v2, wlvP[2], fmaf(v1, wlvP[1], fmaf(pacc, wlvP[0], blvr))));
    __builtin_nontemporal_store(mu, out + (size_t)r * 64 + lane);
    __builtin_nontemporal_store(lv, out + lv_base + (size_t)r * 64 + lane);
  }
}

extern "C" void kernel_launch(void* const* d_in, const int* in_sizes, int n_in,
                              void* d_out, int out_size, void* d_ws, size_t ws_size,
                              hipStream_t stream) {
  const float* x   = (const float*)d_in[0];
  const float* W1  = (const float*)d_in[1];
  const float* b1  = (const float*)d_in[2];
  const float* qp  = (const float*)d_in[3];
  const float* Wmu = (const float*)d_in[4];
  const float* bmu = (const float*)d_in[5];
  const float* Wlv = (const float*)d_in[6];
  const float* blv = (const float*)d_in[7];
  float* out = (float*)d_out;
  float* dots = (float*)d_ws;  // B*4 floats = 512 KB scratch

  const int B = out_size / 128;  // out = mu(B,64) ++ logvar(B,64)

  // k1: row-per-wave, grid-stride; 2048 blocks x 4 waves = 8 waves/SIMD
  int blocks1 = (B + 3) / 4;
  if (blocks1 > 2048) blocks1 = 2048;
  dots_kernel<<<blocks1, 256, 0, stream>>>(x, W1, dots, B);

  // k2: 4 waves/block, grid-stride rows
  int blocks2 = (B + 31) / 32;
  if (blocks2 > 1024) blocks2 = 1024;
  tail_kernel<<<blocks2, 256, 0, stream>>>(dots, b1, qp, Wmu, bmu, Wlv, blv,
                                           out, B);
}

// Round 18
// 40.672 us; speedup vs baseline: 1.1180x; 1.0649x over previous
//
#include <hip/hip_runtime.h>

typedef float f32x4 __attribute__((ext_vector_type(4)));

#define D_IN 1024

// tanh(x) = 1 - 2/(exp(2x)+1): v_exp + v_rcp, robust for all x
__device__ __forceinline__ float fast_tanh(float x) {
  float e = __expf(2.0f * x);
  return 1.0f - 2.0f * __builtin_amdgcn_rcpf(e + 1.0f);
}

// ---------------------------------------------------------------------------
// DIAGNOSTIC: k1 = round-15's best variant (16 rows/wave, 4 lanes/row,
// 512 blocks) wrapped in REP=4 (idempotent rewrites of dots) so the dispatch
// exceeds the 74us harness-fill profile cutoff and finally yields counters.
// k2 unchanged (validated).
// ---------------------------------------------------------------------------
__global__ __launch_bounds__(256) void dots_kernel(
    const float* __restrict__ x, const float* __restrict__ W1,
    float* __restrict__ dots, int B) {
  __shared__ f32x4 W1L[1024];  // W1L[j*256 + i] = W1[j][4i..4i+3]

  const int tid = threadIdx.x;
  {
    const f32x4* wp = reinterpret_cast<const f32x4*>(W1);
#pragma unroll
    for (int k = 0; k < 4; ++k) W1L[k * 256 + tid] = wp[k * 256 + tid];
  }
  __syncthreads();

  const int lane = tid & 63;
  const int p = lane & 3;        // d-phase: owns [g*64 + p*16, +16) for g=0..15
  const int wave = blockIdx.x * 4 + (tid >> 6);
  const int row = wave * 16 + (lane >> 2);
  if (row >= B) return;

  const float* xr = x + (size_t)row * D_IN;

  for (int rep = 0; rep < 4; ++rep) {
    float acc[4] = {0.f, 0.f, 0.f, 0.f};

#pragma unroll
    for (int g = 0; g < 16; ++g) {
      const int db = g * 64 + p * 16;  // float index of this lane's 16-float slice
      f32x4 xv[4];
#pragma unroll
      for (int k = 0; k < 4; ++k)
        xv[k] = *reinterpret_cast<const f32x4*>(xr + db + 4 * k);
#pragma unroll
      for (int k = 0; k < 4; ++k) {
        const int wi = (db >> 2) + k;
        f32x4 xk = xv[k];
#pragma unroll
        for (int j = 0; j < 4; ++j) {
          f32x4 w = W1L[j * 256 + wi];
          acc[j] = fmaf(xk.x, w.x, acc[j]);
          acc[j] = fmaf(xk.y, w.y, acc[j]);
          acc[j] = fmaf(xk.z, w.z, acc[j]);
          acc[j] = fmaf(xk.w, w.w, acc[j]);
        }
      }
    }

    // reduce each dot over the 4 phase-lanes (2 butterfly levels)
#pragma unroll
    for (int j = 0; j < 4; ++j) {
      acc[j] += __shfl_xor(acc[j], 1);
      acc[j] += __shfl_xor(acc[j], 2);
    }
    // lane p stores feature p -> dots[row][p]; 16B per row, coalesced
    float outv = (p == 0) ? acc[0] : (p == 1) ? acc[1] : (p == 2) ? acc[2] : acc[3];
    dots[(size_t)row * 4 + p] = outv;
  }
}

// ---------------------------------------------------------------------------
// k2: tail (unchanged, validated). Per row: uniform 16B load of dots[r] ->
// tanh/sincos -> rank-1 product state -> qf_i = s^T M_i s -> mu/logvar.
// ---------------------------------------------------------------------------
__global__ __launch_bounds__(256) void tail_kernel(
    const float* __restrict__ dots, const float* __restrict__ b1,
    const float* __restrict__ theta,
    const float* __restrict__ Wmu, const float* __restrict__ bmu,
    const float* __restrict__ Wlv, const float* __restrict__ blv,
    float* __restrict__ out, int B) {
  __shared__ float Vre[16][17];
  __shared__ float Vim[16][17];
  __shared__ float Mlds[4][16][16];

  const int tid = threadIdx.x;

  // ---- prologue: evolve V on threads 0..15 ----
  if (tid < 16) {
    float re[16], im[16];
#pragma unroll
    for (int z = 0; z < 16; ++z) { re[z] = 0.f; im[z] = 0.f; }
    re[tid] = 1.f;
    for (int layer = 0; layer < 2; ++layer) {
#pragma unroll
      for (int q = 0; q < 4; ++q) {
        float th = theta[layer * 4 + q];
        float s, c;
        __sincosf(0.5f * th, &s, &c);
        // Rx
#pragma unroll
        for (int z = 0; z < 16; ++z) {
          if (!((z >> q) & 1)) {
            int z1 = z | (1 << q);
            float ar = re[z], ai = im[z], br = re[z1], bi = im[z1];
            re[z]  = c * ar + s * bi;  im[z]  = c * ai - s * br;
            re[z1] = c * br + s * ai;  im[z1] = c * bi - s * ar;
          }
        }
        // Ry
#pragma unroll
        for (int z = 0; z < 16; ++z) {
          if (!((z >> q) & 1)) {
            int z1 = z | (1 << q);
            float ar = re[z], ai = im[z], br = re[z1], bi = im[z1];
            re[z]  = c * ar - s * br;  im[z]  = c * ai - s * bi;
            re[z1] = s * ar + c * br;  im[z1] = s * ai + c * bi;
          }
        }
        // Rz
#pragma unroll
        for (int z = 0; z < 16; ++z) {
          if (!((z >> q) & 1)) {
            int z1 = z | (1 << q);
            float ar = re[z], ai = im[z], br = re[z1], bi = im[z1];
            re[z]  = c * ar + s * ai;  im[z]  = c * ai - s * ar;
            re[z1] = c * br - s * bi;  im[z1] = c * bi + s * br;
          }
        }
      }
      // CNOT ring (0,1)(1,2)(2,3)(3,0)
      const int cqs[4] = {0, 1, 2, 3};
      const int tqs[4] = {1, 2, 3, 0};
#pragma unroll
      for (int gIdx = 0; gIdx < 4; ++gIdx) {
#pragma unroll
        for (int z = 0; z < 16; ++z) {
          if (((z >> cqs[gIdx]) & 1) && !((z >> tqs[gIdx]) & 1)) {
            int z1 = z | (1 << tqs[gIdx]);
            float tr = re[z], ti = im[z];
            re[z] = re[z1];  im[z] = im[z1];
            re[z1] = tr;     im[z1] = ti;
          }
        }
      }
    }
#pragma unroll
    for (int z = 0; z < 16; ++z) { Vre[z][tid] = re[z]; Vim[z][tid] = im[z]; }
  }
  __syncthreads();

  // ---- prologue: M formation ----
  {
    const int i = tid >> 6, a = (tid >> 2) & 15, b0 = (tid & 3) * 4;
    float ra[16], ia[16];
#pragma unroll
    for (int z = 0; z < 16; ++z) { ra[z] = Vre[z][a]; ia[z] = Vim[z][a]; }
#pragma unroll
    for (int k = 0; k < 4; ++k) {
      const int b = b0 + k;
      float acc = 0.f;
#pragma unroll
      for (int z = 0; z < 16; ++z) {
        float sg = ((z >> (3 - i)) & 1) ? -1.f : 1.f;
        acc += sg * (ra[z] * Vre[z][b] + ia[z] * Vim[z][b]);
      }
      Mlds[i][a][b] = acc;
    }
  }
  __syncthreads();

  // ---- main-loop invariants ----
  const int lane = tid & 63;
  const int wave = blockIdx.x * 4 + (tid >> 6);
  const int nwaves = gridDim.x * 4;
  const int g = lane >> 4;
  const int mz = lane & 15;

  float Mr[16];
#pragma unroll
  for (int k = 0; k < 16; ++k) Mr[k] = Mlds[g][mz][k];

  float b1r[4];
#pragma unroll
  for (int j = 0; j < 4; ++j) b1r[j] = b1[j];

  float wmuP[4], wlvP[4];
#pragma unroll
  for (int k = 0; k < 4; ++k) {
    wmuP[k] = Wmu[lane * 4 + (g ^ k)];
    wlvP[k] = Wlv[lane * 4 + (g ^ k)];
  }
  const float bmur = bmu[lane], blvr = blv[lane];
  const size_t lv_base = (size_t)B * 64;

  for (int r = wave; r < B; r += nwaves) {
    const float4 dv = *reinterpret_cast<const float4*>(dots + (size_t)r * 4);

    // ---- angles -> half-angle (cos, sin) ----
    float cq[4], sq[4];
    __sincosf(0.5f * fast_tanh(dv.x + b1r[0]), &sq[0], &cq[0]);
    __sincosf(0.5f * fast_tanh(dv.y + b1r[1]), &sq[1], &cq[1]);
    __sincosf(0.5f * fast_tanh(dv.z + b1r[2]), &sq[2], &cq[2]);
    __sincosf(0.5f * fast_tanh(dv.w + b1r[3]), &sq[3], &cq[3]);

    // rank-1 factors of the product state: sv[z] = A[z&3] * Bf[z>>2]
    const float A0 = cq[0] * cq[1], A1 = sq[0] * cq[1];
    const float A2 = cq[0] * sq[1], A3 = sq[0] * sq[1];
    const float B0 = cq[2] * cq[3], B1 = sq[2] * cq[3];
    const float B2 = cq[2] * sq[3], B3 = sq[2] * sq[3];

    // tdot = M_g[mz][:] . sv
    float t0 = fmaf(Mr[3], A3, fmaf(Mr[2], A2, fmaf(Mr[1], A1, Mr[0] * A0)));
    float t1 = fmaf(Mr[7], A3, fmaf(Mr[6], A2, fmaf(Mr[5], A1, Mr[4] * A0)));
    float t2 = fmaf(Mr[11], A3, fmaf(Mr[10], A2, fmaf(Mr[9], A1, Mr[8] * A0)));
    float t3 = fmaf(Mr[15], A3, fmaf(Mr[14], A2, fmaf(Mr[13], A1, Mr[12] * A0)));
    float tdot = fmaf(t3, B3, fmaf(t2, B2, fmaf(t1, B1, t0 * B0)));

    // sv[mz] via per-bit selects
    float svm = ((mz & 1) ? sq[0] : cq[0]);
    svm *= ((mz & 2) ? sq[1] : cq[1]);
    svm *= ((mz & 4) ? sq[2] : cq[2]);
    svm *= ((mz & 8) ? sq[3] : cq[3]);

    float pacc = tdot * svm;
#pragma unroll
    for (int off = 8; off; off >>= 1) pacc += __shfl_xor(pacc, off);
    // pacc = qf_g; exchange across 16-lane groups
    float v1 = __shfl_xor(pacc, 16);  // qf_{g^1}
    float v2 = __shfl_xor(pacc, 32);  // qf_{g^2}
    float v3 = __shfl_xor(v1, 32);    // qf_{g^3}

    float mu = fmaf(v3, wmuP[3], fmaf(v2, wmuP[2], fmaf(v1, wmuP[1], fmaf(pacc, wmuP[0], bmur))));
    float lv = fmaf(v3, wlvP[3], fmaf(v2, wlvP[2], fmaf(v1, wlvP[1], fmaf(pacc, wlvP[0], blvr))));
    __builtin_nontemporal_store(mu, out + (size_t)r * 64 + lane);
    __builtin_nontemporal_store(lv, out + lv_base + (size_t)r * 64 + lane);
  }
}

extern "C" void kernel_launch(void* const* d_in, const int* in_sizes, int n_in,
                              void* d_out, int out_size, void* d_ws, size_t ws_size,
                              hipStream_t stream) {
  const float* x   = (const float*)d_in[0];
  const float* W1  = (const float*)d_in[1];
  const float* b1  = (const float*)d_in[2];
  const float* qp  = (const float*)d_in[3];
  const float* Wmu = (const float*)d_in[4];
  const float* bmu = (const float*)d_in[5];
  const float* Wlv = (const float*)d_in[6];
  const float* blv = (const float*)d_in[7];
  float* out = (float*)d_out;
  float* dots = (float*)d_ws;  // B*4 floats = 512 KB scratch

  const int B = out_size / 128;  // out = mu(B,64) ++ logvar(B,64)

  // k1: 16 rows/wave, 4 waves/block -> 64 rows/block (round-15 shape, REP=4)
  int blocks1 = (B + 63) / 64;
  dots_kernel<<<blocks1, 256, 0, stream>>>(x, W1, dots, B);

  // k2: 4 waves/block, grid-stride rows
  int blocks2 = (B + 31) / 32;
  if (blocks2 > 1024) blocks2 = 1024;
  tail_kernel<<<blocks2, 256, 0, stream>>>(dots, b1, qp, Wmu, bmu, Wlv, blv,
                                           out, B);
}